// Round 5
// baseline (127.575 us; speedup 1.0000x reference)
//
#include <hip/hip_runtime.h>

#define BB 8
#define NN 128
#define CC 32

struct Params {
  const float* __restrict__ atom0; const float* __restrict__ atom1; const float* __restrict__ atom2;
  const float* __restrict__ edge0; const float* __restrict__ edge1; const float* __restrict__ edge2;
  const void*  mask;
  const float* __restrict__ cg[14];
  const float* __restrict__ w0; const float* __restrict__ w1; const float* __restrict__ w2;
  float* __restrict__ out;
};

// Fused single kernel: block = (b,i), 512 threads = 32 c x 16 slots.
// slot s: sx = s>>3 (wave-uniform: waves 0-3 do x-rows 0..3, waves 4-7 rows 4..8),
//         jp = s&7 (j-slot). Main loop: 3-deep register prefetch rotation.
__global__ __launch_bounds__(512, 4) void lgn_fused(Params p) {
  const int tid = threadIdx.x;
  const int c   = tid & 31;
  const int s   = tid >> 5;      // 0..15
  const int sx  = s >> 3;        // wave-uniform
  const int jp  = s & 7;
  const int blk = blockIdx.x;
  const int b   = blk & 7;       // XCD-friendly
  const int i   = blk >> 3;

  // phase1: two reduce slabs @ [0..5759] (slab = 45q x 64col)
  // phase2: O flat [0..2591] | cat [2592..5951] | mix [5952..8255]
  __shared__ float sm_big[8256];
  __shared__ float sm_cg[540];
  __shared__ float sm_ai[288];
  __shared__ int   sm_list[128];
  __shared__ int   sm_nact, sm_mode;

  // ---- probe mask dtype ----
  if (tid == 0) { sm_mode = 0; sm_list[0] = 0; }
  __syncthreads();
  if (tid < 64) {
    unsigned v = ((const unsigned*)p.mask)[tid];
    if (v == 0x3F800000u) atomicOr(&sm_mode, 2);   // float32
    else if (v > 1u)      atomicOr(&sm_mode, 1);   // packed bytes
  }
  // ---- stage cg + node-i atoms ----
  {
    constexpr int CGSZ[14] = {1,9,25, 9,9,27,45,45, 25,45,75,25,75,125};
    constexpr int CGOF[14] = {0,1,10, 35,44,53,80,125, 170,195,240,315,340,415};
    #pragma unroll
    for (int t = 0; t < 14; ++t)
      for (int idx = tid; idx < CGSZ[t]; idx += 512)
        sm_cg[CGOF[t] + idx] = p.cg[t][idx];
    const int nodeBase = (b * NN + i) * CC;
    for (int s2 = tid; s2 < 288; s2 += 512) {
      int cc = s2 / 9, comp = s2 - cc * 9;
      float v;
      if (comp == 0)      v = p.atom0[nodeBase + cc];
      else if (comp < 4)  v = p.atom1[(nodeBase + cc) * 3 + comp - 1];
      else                v = p.atom2[(nodeBase + cc) * 5 + comp - 4];
      sm_ai[s2] = v;
    }
  }
  __syncthreads();
  const int mode = (sm_mode & 2) ? 2 : sm_mode;

  // ---- ballot compaction of full 128-j row (wave 0) ----
  if (tid < 64) {
    const int row = (b * NN + i) * NN;
    bool mv0, mv1;
    if (mode == 0) {
      mv0 = ((const int*)p.mask)[row + tid] != 0;
      mv1 = ((const int*)p.mask)[row + tid + 64] != 0;
    } else if (mode == 2) {
      mv0 = ((const float*)p.mask)[row + tid] != 0.f;
      mv1 = ((const float*)p.mask)[row + tid + 64] != 0.f;
    } else {
      mv0 = ((const unsigned char*)p.mask)[row + tid] != 0;
      mv1 = ((const unsigned char*)p.mask)[row + tid + 64] != 0;
    }
    unsigned long long b0 = __ballot(mv0);
    unsigned long long b1 = __ballot(mv1);
    int n0 = (int)__popcll(b0);
    unsigned long long lt = (1ull << tid) - 1ull;
    if (mv0) sm_list[__popcll(b0 & lt)] = tid;
    if (mv1) sm_list[n0 + __popcll(b1 & lt)] = tid + 64;
    if (tid == 0) sm_nact = n0 + (int)__popcll(b1);
  }
  __syncthreads();
  const int nact = sm_nact;
  const int nt   = (nact + 7) >> 3;

  // ---- main neighbor loop: 3-deep register prefetch rotation ----
  float acc[5][9];
  #pragma unroll
  for (int k = 0; k < 5; ++k)
    #pragma unroll
    for (int y = 0; y < 9; ++y) acc[k][y] = 0.f;

  const float* e0b = p.edge0 + ((long)(b * NN + i) * NN) * CC + c;
  const float* e1b = p.edge1 + (((long)(b * NN + i) * NN) * CC + c) * 3;
  const float* e2b = p.edge2 + (((long)(b * NN + i) * NN) * CC + c) * 5;
  const float* a0b = p.atom0 +  b * NN * CC + c;
  const float* a1b = p.atom1 + (b * NN * CC + c) * 3;
  const float* a2b = p.atom2 + (b * NN * CC + c) * 5;

#define PREFETCH(Ee, Aa, Wt, T) do {                                        \
    const int idx_ = (T) * 8 + jp;                                          \
    const int j_   = sm_list[idx_ < nact ? idx_ : 0];                       \
    Wt = (idx_ < nact) ? 1.f : 0.f;                                         \
    Ee[0] = e0b[j_ * 32];                                                   \
    { const float* ep_ = e1b + j_ * 96;                                     \
      Ee[1] = ep_[0]; Ee[2] = ep_[1]; Ee[3] = ep_[2]; }                     \
    { const float* ep_ = e2b + j_ * 160;                                    \
      Ee[4] = ep_[0]; Ee[5] = ep_[1]; Ee[6] = ep_[2];                       \
      Ee[7] = ep_[3]; Ee[8] = ep_[4]; }                                     \
    if (sx == 0) {                                                          \
      Aa[0] = a0b[j_ * 32];                                                 \
      const float* ap_ = a1b + j_ * 96;                                     \
      Aa[1] = ap_[0]; Aa[2] = ap_[1]; Aa[3] = ap_[2]; Aa[4] = 0.f;          \
    } else {                                                                \
      const float* ap_ = a2b + j_ * 160;                                    \
      Aa[0] = ap_[0]; Aa[1] = ap_[1]; Aa[2] = ap_[2];                       \
      Aa[3] = ap_[3]; Aa[4] = ap_[4];                                       \
    }                                                                       \
  } while (0)

#define DOFMA(Ee, Aa, Wt) do {                                              \
    if (sx == 0) {                                                          \
      _Pragma("unroll")                                                     \
      for (int k = 0; k < 4; ++k) {                                         \
        const float av_ = Aa[k] * Wt;                                       \
        _Pragma("unroll")                                                   \
        for (int y = 0; y < 9; ++y) acc[k][y] += av_ * Ee[y];               \
      }                                                                     \
    } else {                                                                \
      _Pragma("unroll")                                                     \
      for (int k = 0; k < 5; ++k) {                                         \
        const float av_ = Aa[k] * Wt;                                       \
        _Pragma("unroll")                                                   \
        for (int y = 0; y < 9; ++y) acc[k][y] += av_ * Ee[y];               \
      }                                                                     \
    }                                                                       \
  } while (0)

  {
    float eA[9], aA[5], wtA;
    float eB[9], aB[5], wtB;
    float eC[9], aC[5], wtC;
    PREFETCH(eA, aA, wtA, 0);
    PREFETCH(eB, aB, wtB, 1);
    const int ntr = ((nt + 2) / 3) * 3;
    for (int t = 0; t < ntr; t += 3) {
      PREFETCH(eC, aC, wtC, t + 2);
      DOFMA(eA, aA, wtA);
      PREFETCH(eA, aA, wtA, t + 3);
      DOFMA(eB, aB, wtB);
      PREFETCH(eB, aB, wtB, t + 4);
      DOFMA(eC, aC, wtC);
    }
  }
#undef PREFETCH
#undef DOFMA

  // ---- tree reduce 8 jp-slots (2 slabs of 45x64) ----
  const int sc = sx * 32 + c;
  if (jp >= 6) {
    float* sp = &sm_big[(jp - 6) * 2880 + sc];
    #pragma unroll
    for (int k = 0; k < 5; ++k)
      #pragma unroll
      for (int y = 0; y < 9; ++y) sp[(k * 9 + y) * 64] = acc[k][y];
  }
  __syncthreads();
  if (jp == 4 || jp == 5) {
    const float* sp = &sm_big[(jp - 4) * 2880 + sc];
    #pragma unroll
    for (int k = 0; k < 5; ++k)
      #pragma unroll
      for (int y = 0; y < 9; ++y) acc[k][y] += sp[(k * 9 + y) * 64];
  }
  __syncthreads();
  if (jp == 4 || jp == 5) {
    float* sp = &sm_big[(jp - 4) * 2880 + sc];
    #pragma unroll
    for (int k = 0; k < 5; ++k)
      #pragma unroll
      for (int y = 0; y < 9; ++y) sp[(k * 9 + y) * 64] = acc[k][y];
  }
  __syncthreads();
  if (jp <= 1) {
    const float* sp = &sm_big[jp * 2880 + sc];
    #pragma unroll
    for (int k = 0; k < 5; ++k)
      #pragma unroll
      for (int y = 0; y < 9; ++y) acc[k][y] += sp[(k * 9 + y) * 64];
  }
  __syncthreads();
  if (jp == 2 || jp == 3) {
    float* sp = &sm_big[(jp - 2) * 2880 + sc];
    #pragma unroll
    for (int k = 0; k < 5; ++k)
      #pragma unroll
      for (int y = 0; y < 9; ++y) sp[(k * 9 + y) * 64] = acc[k][y];
  }
  __syncthreads();
  if (jp <= 1) {
    const float* sp = &sm_big[jp * 2880 + sc];
    #pragma unroll
    for (int k = 0; k < 5; ++k)
      #pragma unroll
      for (int y = 0; y < 9; ++y) acc[k][y] += sp[(k * 9 + y) * 64];
  }
  #pragma unroll
  for (int k = 0; k < 5; ++k)
    #pragma unroll
    for (int y = 0; y < 9; ++y) acc[k][y] += __shfl_down(acc[k][y], 32);
  __syncthreads();   // all slab reads done before O overwrites region

  // ---- write final O flat [c][x*9+y] at sm_big[0..2591] ----
  if (s == 0) {
    #pragma unroll
    for (int k = 0; k < 4; ++k)
      #pragma unroll
      for (int y = 0; y < 9; ++y) sm_big[c * 81 + k * 9 + y] = acc[k][y];
  } else if (s == 8) {
    #pragma unroll
    for (int k = 0; k < 5; ++k)
      #pragma unroll
      for (int y = 0; y < 9; ++y) sm_big[c * 81 + (4 + k) * 9 + y] = acc[k][y];
  }
  __syncthreads();

  // ---- build cat (aggregate | identity | power) at sm_big[2592..] ----
  {
    constexpr int colL[31]   = {0,0,0,0,0,0,0, 1,1,1,1,1,1,1,1,1,1,1, 2,2,2,2,2,2,2,2,2,2,2,2,2};
    constexpr int colKind[31]= {0,0,0,1,2,2,2, 0,0,0,0,0,1,2,2,2,2,2, 0,0,0,0,0,0,1,2,2,2,2,2,2};
    constexpr int colL1[31]  = {0,1,2,0,0,1,2, 0,1,1,1,2,0,0,1,1,1,2, 0,1,1,2,2,2,0,0,1,1,2,2,2};
    constexpr int colL2[31]  = {0,1,2,0,0,1,2, 1,0,1,2,1,0,1,0,1,2,1, 2,1,2,0,1,2,0,2,1,2,0,1,2};
    constexpr int colCg[31]  = {0,1,10,0,0,1,10, 35,44,53,80,125,0,35,44,53,80,125,
                                170,195,240,315,340,415,0,170,195,240,315,340,415};
    constexpr int colP[31]   = {0,1,2,3,4,5,6, 0,1,2,3,4,5,6,7,8,9,10, 0,1,2,3,4,5,6,7,8,9,10,11,12};
    constexpr int DD[3]      = {1,3,5};
    constexpr int catBase[3] = {0,224,1280};
    constexpr int aOff[3]    = {0,1,4};

    for (int col = s; col < 31; col += 16) {
      const int l = colL[col];
      const int d = DD[l];
      const int kind = colKind[col];
      float* catp = &sm_big[2592 + catBase[l] + (colP[col] * CC + c) * d];
      if (kind == 1) {            // identity
        for (int z = 0; z < d; ++z) catp[z] = sm_ai[c * 9 + aOff[l] + z];
      } else if (kind == 0) {     // aggregate: contract O(flat x*9+y) with cg
        const int l1 = colL1[col], l2 = colL2[col];
        const int d1 = DD[l1], d2 = DD[l2];
        const int x0 = aOff[l1], y0 = aOff[l2];
        const float* cgp = &sm_cg[colCg[col]];
        const float* Ofl = &sm_big[c * 81];
        for (int z = 0; z < d; ++z) {
          float sum = 0.f;
          for (int xi = 0; xi < d1; ++xi)
            for (int yi = 0; yi < d2; ++yi)
              sum += Ofl[(x0 + xi) * 9 + y0 + yi] * cgp[(xi * d2 + yi) * d + z];
          catp[z] = sum;
        }
      } else {                    // power: atom_i x atom_i
        const int l1 = colL1[col], l2 = colL2[col];
        const int d1 = DD[l1], d2 = DD[l2];
        const float* cgp = &sm_cg[colCg[col]];
        const float* a1p = &sm_ai[c * 9 + aOff[l1]];
        const float* a2p = &sm_ai[c * 9 + aOff[l2]];
        for (int z = 0; z < d; ++z) {
          float sum = 0.f;
          for (int xi = 0; xi < d1; ++xi)
            for (int yi = 0; yi < d2; ++yi)
              sum += a1p[xi] * a2p[yi] * cgp[(xi * d2 + yi) * d + z];
          catp[z] = sum;
        }
      }
    }
  }
  __syncthreads();

  // ---- channel mix (16-way k-split, shfl pair-combine -> 8 partials) ----
  {
    float accm[9];
    #pragma unroll
    for (int q = 0; q < 9; ++q) accm[q] = 0.f;
    const int co = c;
    #pragma unroll
    for (int k0 = 0; k0 < 224; k0 += 16) {
      const int k = k0 + s;
      accm[0] += sm_big[2592 + k] * p.w0[k * CC + co];
    }
    #pragma unroll
    for (int k0 = 0; k0 < 352; k0 += 16) {
      const int k = k0 + s;
      float wv = p.w1[k * CC + co];
      accm[1] += sm_big[2592 + 224 + k * 3 + 0] * wv;
      accm[2] += sm_big[2592 + 224 + k * 3 + 1] * wv;
      accm[3] += sm_big[2592 + 224 + k * 3 + 2] * wv;
    }
    #pragma unroll
    for (int k0 = 0; k0 < 416; k0 += 16) {
      const int k = k0 + s;
      float wv = p.w2[k * CC + co];
      #pragma unroll
      for (int z = 0; z < 5; ++z)
        accm[4 + z] += sm_big[2592 + 1280 + k * 5 + z] * wv;
    }
    #pragma unroll
    for (int q = 0; q < 9; ++q) accm[q] += __shfl_down(accm[q], 32);
    if ((s & 1) == 0) {
      #pragma unroll
      for (int q = 0; q < 9; ++q)
        sm_big[5952 + (s >> 1) * 288 + co * 9 + q] = accm[q];
    }
  }
  __syncthreads();

  // ---- final partial-sum + store ----
  if (tid < 288) {
    float v = 0.f;
    #pragma unroll
    for (int gg = 0; gg < 8; ++gg) v += sm_big[5952 + gg * 288 + tid];
    const int co = tid / 9, zz = tid - co * 9;
    const int nb = (b * NN + i) * CC;
    int oidx;
    if (zz == 0)     oidx = nb + co;                          // l=0
    else if (zz < 4) oidx = 32768  + (nb + co) * 3 + (zz - 1); // l=1
    else             oidx = 131072 + (nb + co) * 5 + (zz - 4); // l=2
    p.out[oidx] = v;
  }
}

extern "C" void kernel_launch(void* const* d_in, const int* in_sizes, int n_in,
                              void* d_out, int out_size, void* d_ws, size_t ws_size,
                              hipStream_t stream) {
  Params p;
  const bool interleaved = (in_sizes[1] == BB * NN * NN * CC);
  if (interleaved) {
    p.atom0 = (const float*)d_in[0]; p.edge0 = (const float*)d_in[1];
    p.atom1 = (const float*)d_in[2]; p.edge1 = (const float*)d_in[3];
    p.atom2 = (const float*)d_in[4]; p.edge2 = (const float*)d_in[5];
  } else {
    p.atom0 = (const float*)d_in[0]; p.atom1 = (const float*)d_in[1]; p.atom2 = (const float*)d_in[2];
    p.edge0 = (const float*)d_in[3]; p.edge1 = (const float*)d_in[4]; p.edge2 = (const float*)d_in[5];
  }
  p.mask = d_in[6];
  for (int t = 0; t < 14; ++t) p.cg[t] = (const float*)d_in[7 + t];
  p.w0 = (const float*)d_in[21];
  p.w1 = (const float*)d_in[22];
  p.w2 = (const float*)d_in[23];
  p.out = (float*)d_out;

  lgn_fused<<<dim3(BB * NN), dim3(512), 0, stream>>>(p);
}

// Round 6
// 67.321 us; speedup vs baseline: 1.8950x; 1.8950x over previous
//
#include <hip/hip_runtime.h>

#define BB 8
#define NN 128
#define CC 32

struct Params {
  const float* __restrict__ atom0; const float* __restrict__ atom1; const float* __restrict__ atom2;
  const float* __restrict__ edge0; const float* __restrict__ edge1; const float* __restrict__ edge2;
  const void*  mask;
  const float* __restrict__ cg[14];
  const float* __restrict__ w0; const float* __restrict__ w1; const float* __restrict__ w2;
  float* __restrict__ out;
};

// Block = (b,i), 512 threads = 32 c x 16 slots (sx = x-half, jp = j-slot).
// Main loop: groups of 8 j staged cooperatively into LDS (float4, coalesced,
// double-buffered), consumed via conflict-free scalar ds_reads.
// Staged row layout per j (576 floats): [a0:0][a1:32][a2:128][e0:288][e1:320][e2:416]
__global__ __launch_bounds__(512, 2) void lgn_fused(Params p) {
  const int tid = threadIdx.x;
  const int c   = tid & 31;
  const int s   = tid >> 5;      // 0..15
  const int sx  = s >> 3;        // wave-uniform x-half
  const int jp  = s & 7;         // j-slot
  const int blk = blockIdx.x;
  const int b   = blk & 7;       // XCD-friendly
  const int i   = blk >> 3;

  // arena phases: (1) stage dbuf 2x4608 | (2) reduce slabs 2x2880 | (3) O 0..2591, cat 2592..5951, mix 5952..8255
  __shared__ float arena[9216];
  __shared__ float sm_cg[540];
  __shared__ float sm_ai[288];
  __shared__ int   sm_list[128];
  __shared__ int   sm_nact, sm_mode;

  // ---- probe mask dtype ----
  if (tid == 0) sm_mode = 0;
  __syncthreads();
  if (tid < 64) {
    unsigned v = ((const unsigned*)p.mask)[tid];
    if (v == 0x3F800000u) atomicOr(&sm_mode, 2);   // float32
    else if (v > 1u)      atomicOr(&sm_mode, 1);   // packed bytes
  }
  // ---- stage cg + node-i atoms ----
  {
    constexpr int CGSZ[14] = {1,9,25, 9,9,27,45,45, 25,45,75,25,75,125};
    constexpr int CGOF[14] = {0,1,10, 35,44,53,80,125, 170,195,240,315,340,415};
    #pragma unroll
    for (int t = 0; t < 14; ++t)
      for (int idx = tid; idx < CGSZ[t]; idx += 512)
        sm_cg[CGOF[t] + idx] = p.cg[t][idx];
    const int nodeBase = (b * NN + i) * CC;
    for (int s2 = tid; s2 < 288; s2 += 512) {
      int cc = s2 / 9, comp = s2 - cc * 9;
      float v;
      if (comp == 0)      v = p.atom0[nodeBase + cc];
      else if (comp < 4)  v = p.atom1[(nodeBase + cc) * 3 + comp - 1];
      else                v = p.atom2[(nodeBase + cc) * 5 + comp - 4];
      sm_ai[s2] = v;
    }
  }
  __syncthreads();
  const int mode = (sm_mode & 2) ? 2 : sm_mode;

  // ---- ballot compaction of 128-j mask row (wave 0) ----
  if (tid < 64) {
    const int row = (b * NN + i) * NN;
    bool mv0, mv1;
    if (mode == 0) {
      mv0 = ((const int*)p.mask)[row + tid] != 0;
      mv1 = ((const int*)p.mask)[row + tid + 64] != 0;
    } else if (mode == 2) {
      mv0 = ((const float*)p.mask)[row + tid] != 0.f;
      mv1 = ((const float*)p.mask)[row + tid + 64] != 0.f;
    } else {
      mv0 = ((const unsigned char*)p.mask)[row + tid] != 0;
      mv1 = ((const unsigned char*)p.mask)[row + tid + 64] != 0;
    }
    unsigned long long b0 = __ballot(mv0);
    unsigned long long b1 = __ballot(mv1);
    int n0 = (int)__popcll(b0);
    unsigned long long lt = (1ull << tid) - 1ull;
    if (mv0) sm_list[__popcll(b0 & lt)] = tid;
    if (mv1) sm_list[n0 + __popcll(b1 & lt)] = tid + 64;
    if (tid == 0) sm_nact = n0 + (int)__popcll(b1);
  }
  __syncthreads();
  const int nact = sm_nact;
  const int nt   = (nact + 7) >> 3;
  // pad list to full groups with a valid j
  if (tid < 64) {
    const int j0 = (nact > 0) ? sm_list[0] : 0;
    if (tid      >= nact && tid      < 128) sm_list[tid]      = j0;
    if (tid + 64 >= nact && tid + 64 < 128) sm_list[tid + 64] = j0;
  }
  __syncthreads();

  // ---- staging descriptors (3 float4 rounds per thread; round 2 only tid<128) ----
  const float* srcB[3]; int jmul[3], dstO[3], jgk[3];
  {
    const long ab = (long)b * NN;
    const long eb = (long)(b * NN + i) * NN;
    #pragma unroll
    for (int k = 0; k < 3; ++k) {
      const int f  = tid + k * 512;
      const int jg = f / 144;
      const int r  = f - jg * 144;
      jgk[k] = jg;
      if (r < 8)        { srcB[k] = p.atom0 + ab *  32 + r * 4;        jmul[k] =  32; dstO[k] = jg * 576 +   0 + r * 4; }
      else if (r < 32)  { int q = r - 8;   srcB[k] = p.atom1 + ab *  96 + q * 4; jmul[k] =  96; dstO[k] = jg * 576 +  32 + q * 4; }
      else if (r < 72)  { int q = r - 32;  srcB[k] = p.atom2 + ab * 160 + q * 4; jmul[k] = 160; dstO[k] = jg * 576 + 128 + q * 4; }
      else if (r < 80)  { int q = r - 72;  srcB[k] = p.edge0 + eb *  32 + q * 4; jmul[k] =  32; dstO[k] = jg * 576 + 288 + q * 4; }
      else if (r < 104) { int q = r - 80;  srcB[k] = p.edge1 + eb *  96 + q * 4; jmul[k] =  96; dstO[k] = jg * 576 + 320 + q * 4; }
      else              { int q = r - 104; srcB[k] = p.edge2 + eb * 160 + q * 4; jmul[k] = 160; dstO[k] = jg * 576 + 416 + q * 4; }
    }
  }

  // ---- main loop: stage(t+1) early | consume(t) | ds_write(t+1) late ----
  float acc[5][9];
  #pragma unroll
  for (int k = 0; k < 5; ++k)
    #pragma unroll
    for (int y = 0; y < 9; ++y) acc[k][y] = 0.f;

  if (nt > 0) {
    float4 v0, v1, v2;
    // prologue: stage group 0 into buf 0
    v0 = *(const float4*)(srcB[0] + (long)sm_list[jgk[0]] * jmul[0]);
    v1 = *(const float4*)(srcB[1] + (long)sm_list[jgk[1]] * jmul[1]);
    if (tid < 128) v2 = *(const float4*)(srcB[2] + (long)sm_list[jgk[2]] * jmul[2]);
    *(float4*)(arena + dstO[0]) = v0;
    *(float4*)(arena + dstO[1]) = v1;
    if (tid < 128) *(float4*)(arena + dstO[2]) = v2;
    __syncthreads();

    for (int t = 0; t < nt; ++t) {
      const bool more = (t + 1 < nt);
      if (more) {                              // issue next-group loads early
        const int base = (t + 1) * 8;
        v0 = *(const float4*)(srcB[0] + (long)sm_list[base + jgk[0]] * jmul[0]);
        v1 = *(const float4*)(srcB[1] + (long)sm_list[base + jgk[1]] * jmul[1]);
        if (tid < 128) v2 = *(const float4*)(srcB[2] + (long)sm_list[base + jgk[2]] * jmul[2]);
      }
      // consume current buffer
      {
        const float* bp = arena + (t & 1) * 4608 + jp * 576;
        const float wt = (t * 8 + jp < nact) ? 1.f : 0.f;
        float e[9];
        e[0] = bp[288 + c];
        #pragma unroll
        for (int y = 0; y < 3; ++y) e[1 + y] = bp[320 + c * 3 + y];
        #pragma unroll
        for (int y = 0; y < 5; ++y) e[4 + y] = bp[416 + c * 5 + y];
        if (sx == 0) {
          float a[4];
          a[0] = bp[c];
          #pragma unroll
          for (int y = 0; y < 3; ++y) a[1 + y] = bp[32 + c * 3 + y];
          #pragma unroll
          for (int k = 0; k < 4; ++k) {
            const float av = a[k] * wt;
            #pragma unroll
            for (int y = 0; y < 9; ++y) acc[k][y] += av * e[y];
          }
        } else {
          float a[5];
          #pragma unroll
          for (int y = 0; y < 5; ++y) a[y] = bp[128 + c * 5 + y];
          #pragma unroll
          for (int k = 0; k < 5; ++k) {
            const float av = a[k] * wt;
            #pragma unroll
            for (int y = 0; y < 9; ++y) acc[k][y] += av * e[y];
          }
        }
      }
      if (more) {                              // write next group late
        float* bp = arena + ((t + 1) & 1) * 4608;
        *(float4*)(bp + dstO[0]) = v0;
        *(float4*)(bp + dstO[1]) = v1;
        if (tid < 128) *(float4*)(bp + dstO[2]) = v2;
      }
      __syncthreads();
    }
  }

  // ---- tree reduce 8 jp-slots (2 slabs of 45x64 in arena) ----
  const int sc = sx * 32 + c;
  if (jp >= 6) {
    float* sp = &arena[(jp - 6) * 2880 + sc];
    #pragma unroll
    for (int k = 0; k < 5; ++k)
      #pragma unroll
      for (int y = 0; y < 9; ++y) sp[(k * 9 + y) * 64] = acc[k][y];
  }
  __syncthreads();
  if (jp == 4 || jp == 5) {
    const float* sp = &arena[(jp - 4) * 2880 + sc];
    #pragma unroll
    for (int k = 0; k < 5; ++k)
      #pragma unroll
      for (int y = 0; y < 9; ++y) acc[k][y] += sp[(k * 9 + y) * 64];
  }
  __syncthreads();
  if (jp == 4 || jp == 5) {
    float* sp = &arena[(jp - 4) * 2880 + sc];
    #pragma unroll
    for (int k = 0; k < 5; ++k)
      #pragma unroll
      for (int y = 0; y < 9; ++y) sp[(k * 9 + y) * 64] = acc[k][y];
  }
  __syncthreads();
  if (jp <= 1) {
    const float* sp = &arena[jp * 2880 + sc];
    #pragma unroll
    for (int k = 0; k < 5; ++k)
      #pragma unroll
      for (int y = 0; y < 9; ++y) acc[k][y] += sp[(k * 9 + y) * 64];
  }
  __syncthreads();
  if (jp == 2 || jp == 3) {
    float* sp = &arena[(jp - 2) * 2880 + sc];
    #pragma unroll
    for (int k = 0; k < 5; ++k)
      #pragma unroll
      for (int y = 0; y < 9; ++y) sp[(k * 9 + y) * 64] = acc[k][y];
  }
  __syncthreads();
  if (jp <= 1) {
    const float* sp = &arena[jp * 2880 + sc];
    #pragma unroll
    for (int k = 0; k < 5; ++k)
      #pragma unroll
      for (int y = 0; y < 9; ++y) acc[k][y] += sp[(k * 9 + y) * 64];
  }
  #pragma unroll
  for (int k = 0; k < 5; ++k)
    #pragma unroll
    for (int y = 0; y < 9; ++y) acc[k][y] += __shfl_down(acc[k][y], 32);
  __syncthreads();   // slab reads done before O overwrites

  // ---- write final O flat [c][x*9+y] at arena[0..2591] ----
  if (s == 0) {
    #pragma unroll
    for (int k = 0; k < 4; ++k)
      #pragma unroll
      for (int y = 0; y < 9; ++y) arena[c * 81 + k * 9 + y] = acc[k][y];
  } else if (s == 8) {
    #pragma unroll
    for (int k = 0; k < 5; ++k)
      #pragma unroll
      for (int y = 0; y < 9; ++y) arena[c * 81 + (4 + k) * 9 + y] = acc[k][y];
  }
  __syncthreads();

  // ---- build cat (aggregate | identity | power) at arena[2592..] ----
  {
    constexpr int colL[31]   = {0,0,0,0,0,0,0, 1,1,1,1,1,1,1,1,1,1,1, 2,2,2,2,2,2,2,2,2,2,2,2,2};
    constexpr int colKind[31]= {0,0,0,1,2,2,2, 0,0,0,0,0,1,2,2,2,2,2, 0,0,0,0,0,0,1,2,2,2,2,2,2};
    constexpr int colL1[31]  = {0,1,2,0,0,1,2, 0,1,1,1,2,0,0,1,1,1,2, 0,1,1,2,2,2,0,0,1,1,2,2,2};
    constexpr int colL2[31]  = {0,1,2,0,0,1,2, 1,0,1,2,1,0,1,0,1,2,1, 2,1,2,0,1,2,0,2,1,2,0,1,2};
    constexpr int colCg[31]  = {0,1,10,0,0,1,10, 35,44,53,80,125,0,35,44,53,80,125,
                                170,195,240,315,340,415,0,170,195,240,315,340,415};
    constexpr int colP[31]   = {0,1,2,3,4,5,6, 0,1,2,3,4,5,6,7,8,9,10, 0,1,2,3,4,5,6,7,8,9,10,11,12};
    constexpr int DD[3]      = {1,3,5};
    constexpr int catBase[3] = {0,224,1280};
    constexpr int aOff[3]    = {0,1,4};

    for (int col = s; col < 31; col += 16) {
      const int l = colL[col];
      const int d = DD[l];
      const int kind = colKind[col];
      float* catp = &arena[2592 + catBase[l] + (colP[col] * CC + c) * d];
      if (kind == 1) {            // identity
        for (int z = 0; z < d; ++z) catp[z] = sm_ai[c * 9 + aOff[l] + z];
      } else if (kind == 0) {     // aggregate: contract O(flat x*9+y) with cg
        const int l1 = colL1[col], l2 = colL2[col];
        const int d1 = DD[l1], d2 = DD[l2];
        const int x0 = aOff[l1], y0 = aOff[l2];
        const float* cgp = &sm_cg[colCg[col]];
        const float* Ofl = &arena[c * 81];
        for (int z = 0; z < d; ++z) {
          float sum = 0.f;
          for (int xi = 0; xi < d1; ++xi)
            for (int yi = 0; yi < d2; ++yi)
              sum += Ofl[(x0 + xi) * 9 + y0 + yi] * cgp[(xi * d2 + yi) * d + z];
          catp[z] = sum;
        }
      } else {                    // power: atom_i x atom_i
        const int l1 = colL1[col], l2 = colL2[col];
        const int d1 = DD[l1], d2 = DD[l2];
        const float* cgp = &sm_cg[colCg[col]];
        const float* a1p = &sm_ai[c * 9 + aOff[l1]];
        const float* a2p = &sm_ai[c * 9 + aOff[l2]];
        for (int z = 0; z < d; ++z) {
          float sum = 0.f;
          for (int xi = 0; xi < d1; ++xi)
            for (int yi = 0; yi < d2; ++yi)
              sum += a1p[xi] * a2p[yi] * cgp[(xi * d2 + yi) * d + z];
          catp[z] = sum;
        }
      }
    }
  }
  __syncthreads();

  // ---- channel mix (16-way k-split, shfl pair-combine -> 8 partials) ----
  {
    float accm[9];
    #pragma unroll
    for (int q = 0; q < 9; ++q) accm[q] = 0.f;
    const int co = c;
    #pragma unroll
    for (int k0 = 0; k0 < 224; k0 += 16) {
      const int k = k0 + s;
      accm[0] += arena[2592 + k] * p.w0[k * CC + co];
    }
    #pragma unroll
    for (int k0 = 0; k0 < 352; k0 += 16) {
      const int k = k0 + s;
      float wv = p.w1[k * CC + co];
      accm[1] += arena[2592 + 224 + k * 3 + 0] * wv;
      accm[2] += arena[2592 + 224 + k * 3 + 1] * wv;
      accm[3] += arena[2592 + 224 + k * 3 + 2] * wv;
    }
    #pragma unroll
    for (int k0 = 0; k0 < 416; k0 += 16) {
      const int k = k0 + s;
      float wv = p.w2[k * CC + co];
      #pragma unroll
      for (int z = 0; z < 5; ++z)
        accm[4 + z] += arena[2592 + 1280 + k * 5 + z] * wv;
    }
    #pragma unroll
    for (int q = 0; q < 9; ++q) accm[q] += __shfl_down(accm[q], 32);
    if ((s & 1) == 0) {
      #pragma unroll
      for (int q = 0; q < 9; ++q)
        arena[5952 + (s >> 1) * 288 + co * 9 + q] = accm[q];
    }
  }
  __syncthreads();

  // ---- final partial-sum + store ----
  if (tid < 288) {
    float v = 0.f;
    #pragma unroll
    for (int gg = 0; gg < 8; ++gg) v += arena[5952 + gg * 288 + tid];
    const int co = tid / 9, zz = tid - co * 9;
    const int nb = (b * NN + i) * CC;
    int oidx;
    if (zz == 0)     oidx = nb + co;                           // l=0
    else if (zz < 4) oidx = 32768  + (nb + co) * 3 + (zz - 1); // l=1
    else             oidx = 131072 + (nb + co) * 5 + (zz - 4); // l=2
    p.out[oidx] = v;
  }
}

extern "C" void kernel_launch(void* const* d_in, const int* in_sizes, int n_in,
                              void* d_out, int out_size, void* d_ws, size_t ws_size,
                              hipStream_t stream) {
  Params p;
  const bool interleaved = (in_sizes[1] == BB * NN * NN * CC);
  if (interleaved) {
    p.atom0 = (const float*)d_in[0]; p.edge0 = (const float*)d_in[1];
    p.atom1 = (const float*)d_in[2]; p.edge1 = (const float*)d_in[3];
    p.atom2 = (const float*)d_in[4]; p.edge2 = (const float*)d_in[5];
  } else {
    p.atom0 = (const float*)d_in[0]; p.atom1 = (const float*)d_in[1]; p.atom2 = (const float*)d_in[2];
    p.edge0 = (const float*)d_in[3]; p.edge1 = (const float*)d_in[4]; p.edge2 = (const float*)d_in[5];
  }
  p.mask = d_in[6];
  for (int t = 0; t < 14; ++t) p.cg[t] = (const float*)d_in[7 + t];
  p.w0 = (const float*)d_in[21];
  p.w1 = (const float*)d_in[22];
  p.w2 = (const float*)d_in[23];
  p.out = (float*)d_out;

  lgn_fused<<<dim3(BB * NN), dim3(512), 0, stream>>>(p);
}